// Round 9
// baseline (481.482 us; speedup 1.0000x reference)
//
#include <hip/hip_runtime.h>
#include <cstdint>

// RGPR-GNN (GPR-GNN + RGCN basis-decomp convs) for MI355X.
// R20: R19 transform-first restructure, with the tg_kernel B-staging bug
// fixed (R19 staged only half the 128x128 panel -> uninit LDS -> NaN).
//  Math: out[dst] = relu( T0[dst] + sum_edges w_e * T_{rel_e}[src_e] + bias ),
//  w_e = 1/count(dst,rel_e)  (exact identity; precomputed per edge).
//  - tg_kernel: T[s][N][128] = cur @ {root, W_1..7} (grid 391x8, direct-A,
//    B panel staged 2048x16B chunks / 8 iters, single K=128 slab).
//  - gather_out: per-dst wave, prefetch-16, NO segment walk, writes 12.8MB.
//  - place_kernel emits per-edge {T dword offset, fp32 weight}.
//  - lin1 / final / prep unchanged from R18 (best verified 478.6us).
// Edge sort by (dst,rel) runs ONCE: hist(+rank) -> 3-kernel scan -> placement.

constexpr int N_NODES  = 50000;
constexpr int E_EDGES  = 600000;
constexpr int R_REL    = 7;
constexpr int HID      = 128;
constexpr int IN_C     = 256;
constexpr int L_LAYERS = 3;
constexpr int NR       = N_NODES * R_REL;            // 350000 segments
constexpr int SCANR_BLOCKS = (NR + 255) / 256;       // 1368
constexpr int WSLAB_ELEMS = L_LAYERS * 8 * 128 * 128; // 393216

#define DEVI __device__ __forceinline__

using short8  = __attribute__((ext_vector_type(8))) short;
using floatx4 = __attribute__((ext_vector_type(4))) float;

DEVI unsigned short f2bf(float f) {
  unsigned u = __float_as_uint(f);
  unsigned r = (u + 0x7FFFu + ((u >> 16) & 1u)) >> 16;  // RNE
  return (unsigned short)r;
}
DEVI float bf2f(unsigned short h) { return __uint_as_float(((unsigned)h) << 16); }

// ---------------------------------------------------------------- weight prep
// t < WSLAB_ELEMS: wslabT[l][s][f=128][k=128] (B^T per slab); else w1T.
//   s=0: root[l][k][f]; s=1+r: sum_b comps[l][r][b]*bases[l][b][k][f].
__global__ __launch_bounds__(256) void prep_weights(
    const float* __restrict__ w1,
    const float* __restrict__ comps,   // [L,R,8]
    const float* __restrict__ bases,   // [L,8,128,128]
    const float* __restrict__ roots,   // [L,128,128]
    unsigned short* __restrict__ w1T,
    unsigned short* __restrict__ wslabT)
{
  int t = blockIdx.x * 256 + threadIdx.x;
  if (t < WSLAB_ELEMS) {
    int l    = t >> 17;            // 8*128*128 = 131072 per layer
    int rem  = t & 131071;
    int s    = rem >> 14;          // 128*128 = 16384 per slab
    int rem2 = rem & 16383;
    int f    = rem2 >> 7;
    int k    = rem2 & 127;
    float v;
    if (s == 0) {
      v = roots[((size_t)l * 128 + k) * 128 + f];
    } else {
      int r = s - 1;
      const float* cp = comps + ((size_t)l * R_REL + r) * 8;
      const float* bp = bases + (((size_t)l * 8) * 128 + k) * 128 + f;
      float sacc = 0.f;
#pragma unroll
      for (int b = 0; b < 8; ++b) sacc += cp[b] * bp[(size_t)b * 128 * 128];
      v = sacc;
    }
    wslabT[t] = f2bf(v);
  } else {
    int u = t - WSLAB_ELEMS;
    if (u < HID * IN_C) {
      int m = u >> 8, k = u & 255;
      w1T[m * IN_C + k] = f2bf(w1[k * HID + m]);
    }
  }
}

// ------------------------------------------------- histogram (dst,rel) + rank
__global__ __launch_bounds__(256) void hist_kernel(
    const int* __restrict__ ei, const int* __restrict__ et,
    int* __restrict__ cntRel, int* __restrict__ erank)
{
  int e = blockIdx.x * 256 + threadIdx.x;
  if (e >= E_EDGES) return;
  int seg = ei[E_EDGES + e] * R_REL + et[e];
  erank[e] = atomicAdd(&cntRel[seg], 1);
}

// ---------------------------------------------------------------- scan over NR
__global__ __launch_bounds__(256) void scanA_kernel(
    const int* __restrict__ cnt, int* __restrict__ tmpOff,
    int* __restrict__ blockSums)
{
  __shared__ int s[256];
  int i = blockIdx.x * 256 + threadIdx.x;
  int v = (i < NR) ? cnt[i] : 0;
  s[threadIdx.x] = v;
  __syncthreads();
#pragma unroll
  for (int d = 1; d < 256; d <<= 1) {
    int t = (threadIdx.x >= d) ? s[threadIdx.x - d] : 0;
    __syncthreads();
    s[threadIdx.x] += t;
    __syncthreads();
  }
  if (i < NR) tmpOff[i] = s[threadIdx.x] - v;   // exclusive within block
  if (threadIdx.x == 255) blockSums[blockIdx.x] = s[255];
}

// single block, serial chunks with carry (SCANR_BLOCKS = 1368)
__global__ __launch_bounds__(256) void scanB_kernel(int* __restrict__ bs)
{
  __shared__ int s[256];
  __shared__ int carry;
  if (threadIdx.x == 0) carry = 0;
  __syncthreads();
  for (int base = 0; base < SCANR_BLOCKS; base += 256) {
    int cOld = carry;
    int i = base + threadIdx.x;
    int v = (i < SCANR_BLOCKS) ? bs[i] : 0;
    s[threadIdx.x] = v;
    __syncthreads();
#pragma unroll
    for (int d = 1; d < 256; d <<= 1) {
      int t = (threadIdx.x >= d) ? s[threadIdx.x - d] : 0;
      __syncthreads();
      s[threadIdx.x] += t;
      __syncthreads();
    }
    if (i < SCANR_BLOCKS) bs[i] = s[threadIdx.x] - v + cOld;  // exclusive
    __syncthreads();
    if (threadIdx.x == 0) carry = cOld + s[255];
    __syncthreads();
  }
}

__global__ __launch_bounds__(256) void scanC_kernel(
    const int* __restrict__ tmpOff, const int* __restrict__ blockSums,
    int* __restrict__ drs)
{
  int i = blockIdx.x * 256 + threadIdx.x;
  if (i < NR) drs[i] = tmpOff[i] + blockSums[blockIdx.x];
  if (i == 0) drs[NR] = E_EDGES;
}

// ---------------------------------------------------------------- placement
// Pure scatter, no atomics. Emits per-edge {T dword offset, fp32 weight}.
__global__ __launch_bounds__(256) void place_kernel(
    const int* __restrict__ ei, const int* __restrict__ et,
    const int* __restrict__ drs, const int* __restrict__ erank,
    const int* __restrict__ cntRel,
    uint2* __restrict__ eoffw)
{
  int e = blockIdx.x * 256 + threadIdx.x;
  if (e >= E_EDGES) return;
  int src = ei[e];
  int rel = et[e];
  int seg = ei[E_EDGES + e] * R_REL + rel;
  int pos = drs[seg] + erank[e];
  unsigned off = ((1u + (unsigned)rel) * (unsigned)N_NODES + (unsigned)src) * 64u;
  float w = 1.0f / (float)cntRel[seg];
  eoffw[pos] = make_uint2(off, __float_as_uint(w));
}

// ---------------------------------------------------------------- lin1 MFMA GEMM
// M=64 tile (grid 782), K=256 in 2 phases; x read fp32 + cast DURING staging.
// Output: b0 = bf16(t0*(x@w1+b1)) ONLY (no fp32 hidden).
__global__ __launch_bounds__(256) void gemm_lin1(
    const float* __restrict__ x,              // [N,256] fp32
    const unsigned short* __restrict__ BT,    // w1T [128,256] bf16
    const float* __restrict__ bias,
    const float* __restrict__ temp,
    unsigned short* __restrict__ b0out)       // [N,128] bf16
{
  __shared__ unsigned short Atile[64][136];    // 17.4 KB
  __shared__ unsigned short Btile[128][136];   // 34.8 KB
  const int tid  = threadIdx.x;
  const int row0 = blockIdx.x * 64;
  const int lane = tid & 63;
  const int wid  = tid >> 6;
  const int wrow = (wid & 1) * 32;
  const int wcol = (wid >> 1) * 64;
  const int l15  = lane & 15;
  const int quad = lane >> 4;

  floatx4 acc[2][4] = {};

  for (int k0 = 0; k0 < IN_C; k0 += 128) {
#pragma unroll
    for (int it = 0; it < 4; ++it) {
      int chunk = it * 256 + tid;
      int r = chunk >> 4, cc = (chunk & 15) << 3;
      int grow = row0 + r;
      uint4 va = make_uint4(0u, 0u, 0u, 0u);
      if (grow < N_NODES) {
        const float* xp = x + (size_t)grow * IN_C + k0 + cc;
        float4 f0 = *(const float4*)xp;
        float4 f1 = *(const float4*)(xp + 4);
        va.x = (unsigned)f2bf(f0.x) | ((unsigned)f2bf(f0.y) << 16);
        va.y = (unsigned)f2bf(f0.z) | ((unsigned)f2bf(f0.w) << 16);
        va.z = (unsigned)f2bf(f1.x) | ((unsigned)f2bf(f1.y) << 16);
        va.w = (unsigned)f2bf(f1.z) | ((unsigned)f2bf(f1.w) << 16);
      }
      *(uint4*)(&Atile[r][cc]) = va;
    }
#pragma unroll
    for (int it = 0; it < 8; ++it) {
      int chunk = it * 256 + tid;
      int n = chunk >> 4, cc = (chunk & 15) << 3;
      *(uint4*)(&Btile[n][cc]) =
          *(const uint4*)(BT + (size_t)n * IN_C + k0 + cc);
    }
    __syncthreads();
#pragma unroll
    for (int ks = 0; ks < 4; ++ks) {
      int kc = ks * 32 + quad * 8;
      short8 af[2], bfr[4];
#pragma unroll
      for (int i = 0; i < 2; ++i)
        af[i] = *(const short8*)(&Atile[wrow + i * 16 + l15][kc]);
#pragma unroll
      for (int j = 0; j < 4; ++j)
        bfr[j] = *(const short8*)(&Btile[wcol + j * 16 + l15][kc]);
#pragma unroll
      for (int i = 0; i < 2; ++i)
#pragma unroll
        for (int j = 0; j < 4; ++j)
          acc[i][j] = __builtin_amdgcn_mfma_f32_16x16x32_bf16(
              af[i], bfr[j], acc[i][j], 0, 0, 0);
    }
    __syncthreads();
  }

  float t0 = temp[0];
#pragma unroll
  for (int i = 0; i < 2; ++i) {
    int lrow0 = wrow + i * 16 + quad * 4;
#pragma unroll
    for (int j = 0; j < 4; ++j) {
      int gcol = wcol + j * 16 + l15;
      float bb = bias[gcol];
#pragma unroll
      for (int r = 0; r < 4; ++r)
        Atile[lrow0 + r][gcol] = f2bf(t0 * (acc[i][j][r] + bb));
    }
  }
  __syncthreads();
#pragma unroll
  for (int it = 0; it < 4; ++it) {
    int chunk = it * 256 + tid;
    int r = chunk >> 4, cc = (chunk & 15) << 3;
    int grow = row0 + r;
    if (grow < N_NODES)
      *(uint4*)(b0out + (size_t)grow * HID + cc) = *(const uint4*)(&Atile[r][cc]);
  }
}

// ---------------------------------------------------------------- transform GEMM
// T[s][N][128] = cur @ slab_s. grid (391, 8); slab s = blockIdx.y.
// A direct from global (16B/lane, rows read once per slab, L2/L3-served on
// re-reads across slabs); B panel 128x128 staged once (2048 chunks, 8/thread);
// single K=128 slab. Epilogue: plain bf16 store (bias/relu in gather_out).
__global__ __launch_bounds__(256) void tg_kernel(
    const unsigned short* __restrict__ curA,   // [N,128] bf16 (= b_l)
    const unsigned short* __restrict__ WT,     // wslabT[l] : [8][128][128] bf16
    unsigned short* __restrict__ T)            // [8][N][128] bf16
{
  __shared__ unsigned short Btile[128][136];   // 34.8 KB (B panel / C transpose)
  const int tid  = threadIdx.x;
  const int row0 = blockIdx.x * 128;
  const int s    = blockIdx.y;
  const int lane = tid & 63;
  const int wid  = tid >> 6;
  const int wrow = (wid & 1) * 64;
  const int wcol = (wid >> 1) * 64;
  const int l15  = lane & 15;
  const int quad = lane >> 4;

  const unsigned short* Wp = WT + (size_t)s * 128 * 128;

  // stage B panel: 128 rows x 128 k = 2048 x 16B chunks, 8/thread. (R19 bug
  // was 4 iters with a >>3 decomposition = half the panel; this is the fix.)
#pragma unroll
  for (int it = 0; it < 8; ++it) {
    int chunk = it * 256 + tid;
    int n = chunk >> 4, cc = (chunk & 15) << 3;
    *(uint4*)(&Btile[n][cc]) = *(const uint4*)(Wp + (size_t)n * 128 + cc);
  }
  __syncthreads();

  floatx4 acc[4][4] = {};
#pragma unroll
  for (int ks = 0; ks < 4; ++ks) {
    int kc = ks * 32 + quad * 8;
    short8 af[4], bfr[4];
#pragma unroll
    for (int i = 0; i < 4; ++i) {
      int grow = row0 + wrow + i * 16 + l15;
      short8 v = {};
      if (grow < N_NODES)
        v = *(const short8*)(curA + (size_t)grow * HID + kc);
      af[i] = v;
    }
#pragma unroll
    for (int j = 0; j < 4; ++j)
      bfr[j] = *(const short8*)(&Btile[wcol + j * 16 + l15][kc]);
#pragma unroll
    for (int i = 0; i < 4; ++i)
#pragma unroll
      for (int j = 0; j < 4; ++j)
        acc[i][j] = __builtin_amdgcn_mfma_f32_16x16x32_bf16(
            af[i], bfr[j], acc[i][j], 0, 0, 0);
  }
  __syncthreads();

  // epilogue: bf16(acc) via LDS transpose (Btile reused), then store T slab.
#pragma unroll
  for (int i = 0; i < 4; ++i) {
    int lrow0 = wrow + i * 16 + quad * 4;
#pragma unroll
    for (int j = 0; j < 4; ++j) {
      int gcol = wcol + j * 16 + l15;
#pragma unroll
      for (int r = 0; r < 4; ++r)
        Btile[lrow0 + r][gcol] = f2bf(acc[i][j][r]);
    }
  }
  __syncthreads();
  unsigned short* Tout = T + (size_t)s * N_NODES * HID;
#pragma unroll
  for (int it = 0; it < 8; ++it) {
    int chunk = it * 256 + tid;
    int r = chunk >> 4, cc = (chunk & 15) << 3;
    int grow = row0 + r;
    if (grow < N_NODES)
      *(uint4*)(Tout + (size_t)grow * HID + cc) = *(const uint4*)(&Btile[r][cc]);
  }
}

// ---------------------------------------------------------------- gather + out
// One wave per dst. out[dst] = T0[dst] + sum_e w_e*T[off_e] + bias; relu l<2.
// No segment walk: weights/offsets precomputed per edge. Prefetch-16 MLP.
__global__ __launch_bounds__(256) void gather_out(
    const unsigned short* __restrict__ T,      // [8][N][128] bf16
    const uint2* __restrict__ eoffw,           // sorted by (dst,rel)
    const int* __restrict__ drs,               // [N*R+1] segment starts
    const float* __restrict__ bias,            // [128]
    unsigned short* __restrict__ bout,         // [N,128] bf16 (= b_{l+1})
    int layer)
{
  const int tid  = threadIdx.x;
  const int lane = tid & 63;
  const int dst  = blockIdx.x * 4 + (tid >> 6);
  if (dst >= N_NODES) return;

  int bd = drs[dst * R_REL + ((lane & 1) ? R_REL : 0)];
  const int a0    = __shfl(bd, 0);
  const int total = __shfl(bd, 1) - a0;

  unsigned peo = 0u; int pew = 0;
  if (lane < total) {
    uint2 pe = eoffw[a0 + lane];               // covers total<=64 (deg avg 12)
    peo = pe.x; pew = (int)pe.y;
  }

  const unsigned* Td = (const unsigned*)T;
  float sx = 0.f, sy = 0.f;

  for (int base = 0; base < total; base += 16) {
    const int cnt = min(total - base, 16);
    unsigned uval[16]; float uw[16];
#pragma unroll
    for (int e = 0; e < 16; ++e) {
      if (e < cnt) {
        int idx = base + e;
        unsigned off; float w;
        if (idx < 64) {
          off = (unsigned)__shfl((int)peo, idx);
          w   = __uint_as_float((unsigned)__shfl(pew, idx));
        } else {                                // rare tail: deg > 64
          uint2 pe = eoffw[a0 + idx];
          off = pe.x; w = __uint_as_float(pe.y);
        }
        uw[e]   = w;
        uval[e] = Td[(size_t)off + lane];       // 256B row, coalesced
      }
    }
#pragma unroll
    for (int e = 0; e < 16; ++e) {
      if (e >= cnt) break;
      unsigned u = uval[e];
      sx += uw[e] * __uint_as_float(u << 16);          // lo bf16
      sy += uw[e] * __uint_as_float(u & 0xFFFF0000u);  // hi bf16
    }
  }

  // root term (slab 0) + bias, relu, pack, store.
  unsigned ur = Td[(size_t)dst * 64 + lane];
  sx += __uint_as_float(ur << 16);
  sy += __uint_as_float(ur & 0xFFFF0000u);
  float2 bb = *(const float2*)(bias + lane * 2);
  float c0 = sx + bb.x, c1 = sy + bb.y;
  if (layer < L_LAYERS - 1) { c0 = fmaxf(c0, 0.f); c1 = fmaxf(c1, 0.f); }
  unsigned pck = (unsigned)f2bf(c0) | ((unsigned)f2bf(c1) << 16);
  ((unsigned*)bout)[(size_t)dst * 64 + lane] = pck;
}

// ---------------------------------------------------------------- final linear
// h[d] = b0 + temp[1]*b1 + temp[2]*b2 + temp[3]*b3 (bf16 terms), then lin2.
__global__ __launch_bounds__(256) void final_kernel(
    const unsigned short* __restrict__ b0, const unsigned short* __restrict__ b1,
    const unsigned short* __restrict__ b2v, const unsigned short* __restrict__ b3,
    const float* __restrict__ temp,
    const float* __restrict__ w2, const float* __restrict__ b2bias,
    float* __restrict__ out)
{
  int node = blockIdx.x * 4 + (threadIdx.x >> 6);
  int lane = threadIdx.x & 63;
  if (node >= N_NODES) return;
  float t1 = temp[1], t2 = temp[2], t3 = temp[3];
  size_t base = (size_t)node * 64 + lane;      // uint index: dims 2*lane,2*lane+1
  unsigned u0 = ((const unsigned*)b0)[base];
  unsigned u1 = ((const unsigned*)b1)[base];
  unsigned u2 = ((const unsigned*)b2v)[base];
  unsigned u3 = ((const unsigned*)b3)[base];
  float hx = bf2f((unsigned short)(u0 & 0xFFFF)) +
             t1 * bf2f((unsigned short)(u1 & 0xFFFF)) +
             t2 * bf2f((unsigned short)(u2 & 0xFFFF)) +
             t3 * bf2f((unsigned short)(u3 & 0xFFFF));
  float hy = bf2f((unsigned short)(u0 >> 16)) +
             t1 * bf2f((unsigned short)(u1 >> 16)) +
             t2 * bf2f((unsigned short)(u2 >> 16)) +
             t3 * bf2f((unsigned short)(u3 >> 16));
  int d0 = lane * 2, d1 = lane * 2 + 1;
  float a0 = hx * w2[d0 * 2 + 0] + hy * w2[d1 * 2 + 0];
  float a1 = hx * w2[d0 * 2 + 1] + hy * w2[d1 * 2 + 1];
#pragma unroll
  for (int off = 32; off > 0; off >>= 1) {
    a0 += __shfl_down(a0, off);
    a1 += __shfl_down(a1, off);
  }
  if (lane == 0) {
    out[node * 2 + 0] = a0 + b2bias[0];
    out[node * 2 + 1] = a1 + b2bias[1];
  }
}

// ---------------------------------------------------------------- launcher
extern "C" void kernel_launch(void* const* d_in, const int* in_sizes, int n_in,
                              void* d_out, int out_size, void* d_ws, size_t ws_size,
                              hipStream_t stream) {
  const float* x     = (const float*)d_in[0];
  const int*   ei    = (const int*)d_in[1];
  const int*   et    = (const int*)d_in[2];
  const float* temp  = (const float*)d_in[3];
  const float* w1    = (const float*)d_in[4];
  const float* b1    = (const float*)d_in[5];
  const float* w2    = (const float*)d_in[6];
  const float* b2    = (const float*)d_in[7];
  const float* comps = (const float*)d_in[8];
  const float* bases = (const float*)d_in[9];
  const float* roots = (const float*)d_in[10];
  const float* cbias = (const float*)d_in[11];

  char* ws = (char*)d_ws;
  size_t off = 0;
  auto take = [&](size_t bytes) {
    char* p = ws + off;
    off = (off + bytes + 255) & ~(size_t)255;
    return p;
  };
  unsigned short* wslabT = (unsigned short*)take((size_t)WSLAB_ELEMS * 2); // 0.8 MB
  unsigned short* w1T    = (unsigned short*)take((size_t)HID * IN_C * 2);  // 64 KB
  int*   cntRel  = (int*)take((size_t)NR * 4);                  // 1.4 MB
  int*   tmpOffR = (int*)take((size_t)NR * 4);                  // 1.4 MB
  int*   blockSumsR = (int*)take((size_t)SCANR_BLOCKS * 4);
  int*   drs     = (int*)take((size_t)(NR + 1) * 4);            // 1.4 MB
  int*   erank   = (int*)take((size_t)E_EDGES * 4);             // 2.4 MB
  uint2* eoffw   = (uint2*)take((size_t)E_EDGES * 8);           // 4.8 MB
  unsigned short* bl[L_LAYERS + 1];
  for (int i = 0; i <= L_LAYERS; ++i)
    bl[i] = (unsigned short*)take((size_t)N_NODES * HID * 2);   // 4 x 12.8 MB
  unsigned short* T = (unsigned short*)take((size_t)8 * N_NODES * HID * 2); // 102.4 MB

  hipMemsetAsync(cntRel, 0, (size_t)NR * 4, stream);

  hipLaunchKernelGGL(prep_weights,
                     dim3((WSLAB_ELEMS + HID * IN_C + 255) / 256), dim3(256),
                     0, stream, w1, comps, bases, roots, w1T, wslabT);
  hipLaunchKernelGGL(hist_kernel, dim3((E_EDGES + 255) / 256), dim3(256), 0,
                     stream, ei, et, cntRel, erank);
  hipLaunchKernelGGL(scanA_kernel, dim3(SCANR_BLOCKS), dim3(256), 0, stream,
                     cntRel, tmpOffR, blockSumsR);
  hipLaunchKernelGGL(scanB_kernel, dim3(1), dim3(256), 0, stream, blockSumsR);
  hipLaunchKernelGGL(scanC_kernel, dim3(SCANR_BLOCKS), dim3(256), 0, stream,
                     tmpOffR, blockSumsR, drs);
  hipLaunchKernelGGL(place_kernel, dim3((E_EDGES + 255) / 256), dim3(256), 0,
                     stream, ei, et, drs, erank, cntRel, eoffw);

  const int rowBlocks64  = (N_NODES + 63) / 64;     // 782
  const int rowBlocks128 = (N_NODES + 127) / 128;   // 391
  hipLaunchKernelGGL(gemm_lin1, dim3(rowBlocks64), dim3(256), 0, stream,
                     x, w1T, b1, temp, bl[0]);

  for (int l = 0; l < L_LAYERS; ++l) {
    hipLaunchKernelGGL(tg_kernel, dim3(rowBlocks128, 8), dim3(256), 0, stream,
                       bl[l], wslabT + (size_t)l * 8 * 128 * 128, T);
    hipLaunchKernelGGL(gather_out, dim3((N_NODES + 3) / 4), dim3(256), 0,
                       stream, T, eoffw, drs, cbias + (size_t)l * HID,
                       bl[l + 1], l);
  }

  hipLaunchKernelGGL(final_kernel, dim3((N_NODES + 3) / 4), dim3(256), 0, stream,
                     bl[0], bl[1], bl[2], bl[3], temp, w2, b2, (float*)d_out);
}